// Round 4
// baseline (98.476 us; speedup 1.0000x reference)
//
#include <hip/hip_runtime.h>

#define G 8192
#define IMG_W 512
#define IMG_H 512
#define TILE 16
#define NTX (IMG_W / TILE)
#define NTY (IMG_H / TILE)
#define BLK 256             // range kernel block
#define BLKT 128            // tile kernel block: 2 waves, 2 px per lane
#define CAP 1024            // per-tile list capacity (avg ~190)
#define ALPHA_THRESH (1.0f/255.0f)
#define ALPHA_CAP 0.99f
#define TRANS_THRESH 1e-4f

// -----------------------------------------------------------------------
// Kernel 0: per-gaussian tile-span (exact conservative cull, packed u32)
// PLUS a packed 64B record per gaussian:
//   r[0]=mx r[1]=my r[2]=0.5a r[3]=b r[4]=0.5c r[5]=op r[6..8]=rgb
// Record G (index 8192) is all-zero: op=0 -> exact no-op pad gaussian.
// -----------------------------------------------------------------------
__global__ __launch_bounds__(BLK)
void range_kernel(const float* __restrict__ means2d,
                  const float* __restrict__ conics,
                  const float* __restrict__ colors,
                  const float* __restrict__ opac,
                  unsigned int* __restrict__ ranges,
                  float* __restrict__ tbl)
{
    int g = blockIdx.x * BLK + threadIdx.x;
    if (g >= G) return;
    float op = opac[g];
    float a  = conics[3*g], b = conics[3*g+1], c = conics[3*g+2];
    float mx = means2d[2*g], my = means2d[2*g+1];
    float cr = colors[3*g], cg = colors[3*g+1], cb = colors[3*g+2];

    float4* t4 = (float4*)(tbl + (g << 4));
    t4[0] = make_float4(mx, my, 0.5f * a, b);
    t4[1] = make_float4(0.5f * c, op, cr, cg);
    t4[2] = make_float4(cb, 0.0f, 0.0f, 0.0f);
    if (g == 0) {                       // zero pad-record at index G
        float4* z = (float4*)(tbl + (G << 4));
        z[0] = z[1] = z[2] = make_float4(0.0f, 0.0f, 0.0f, 0.0f);
    }

    unsigned int packed = 0xFFu;          // default: culled
    if (op * 255.0f >= 1.0f) {
        float smax = __logf(op * 255.0f);
        float det = fmaxf(a * c - b * b, 1e-12f);
        float rx = sqrtf(fmaxf(2.0f * smax * c / det, 0.0f)) * 1.0001f + 0.01f;
        float ry = sqrtf(fmaxf(2.0f * smax * a / det, 0.0f)) * 1.0001f + 0.01f;
        int txmin = (int)ceilf ((mx - rx - 15.5f) * 0.0625f);
        int txmax = (int)floorf((mx + rx -  0.5f) * 0.0625f);
        int tymin = (int)ceilf ((my - ry - 15.5f) * 0.0625f);
        int tymax = (int)floorf((my + ry -  0.5f) * 0.0625f);
        if (!(txmax < 0 || txmin > NTX-1 || tymax < 0 || tymin > NTY-1 ||
              txmin > txmax || tymin > tymax)) {
            txmin = max(txmin, 0); txmax = min(txmax, NTX-1);
            tymin = max(tymin, 0); tymax = min(tymax, NTY-1);
            packed = (unsigned)txmin | ((unsigned)txmax << 8)
                   | ((unsigned)tymin << 16) | ((unsigned)tymax << 24);
        }
    }
    ranges[g] = packed;
}

__device__ __forceinline__ int hitp(unsigned p, unsigned btx, unsigned bty)
{
    return (btx >= (p & 0xffu)) & (btx <= ((p >> 8) & 0xffu)) &
           (bty >= ((p >> 16) & 0xffu)) & (bty <= (p >> 24));
}

// -----------------------------------------------------------------------
// Kernel 1 (one 128-thread block per 16x16 tile; 2 waves; 2 px per lane):
//  Phase 1: two-pass scan (16 uint4/lane in registers) + ballot
//           compaction in gaussian-index order.
//  Phase 2: rank sort, 32-bit float-bit keys, POSITION tiebreak; keys
//           read as uint4 -> 1 ds_read_b128 per 4 comparisons.
//  Phase 3: wave-uniform scalar-pipe compositing, 2 vertically-adjacent
//           pixels per lane. Broadcast work (slist ds_read, readfirstlane,
//           record s_loads, __all exit checks) issued per-PAIR -> half the
//           replication of the 4-wave layout; dx/dx2 shared. Per-pixel
//           expression tree identical to the validated version.
// -----------------------------------------------------------------------
__global__ __launch_bounds__(BLKT)
void tile_kernel(const unsigned int* __restrict__ ranges,
                 const float* __restrict__ depths,
                 const float* __restrict__ tbl,
                 float*       __restrict__ out)
{
    __shared__ __align__(16) unsigned short slist[CAP + 4];
    __shared__ __align__(16) unsigned int fkeys[CAP + 4];
    __shared__ int woff[2];

    const int t = threadIdx.x;
    const int lane = t & 63, w = t >> 6;          // w in {0,1}
    const unsigned btx = blockIdx.x, bty = blockIdx.y;

    // ---- Phase 1, pass A: load + count (no barriers) ----
    const uint4* r4 = (const uint4*)ranges;
    const int wbase = w * (G / 2);                // 4096 gaussians per wave
    uint4 rv[16];
    #pragma unroll
    for (int i = 0; i < 16; ++i)
        rv[i] = r4[(wbase >> 2) + i * 64 + lane];

    int cnt = 0;
    #pragma unroll
    for (int i = 0; i < 16; ++i)
        cnt += hitp(rv[i].x, btx, bty) + hitp(rv[i].y, btx, bty)
             + hitp(rv[i].z, btx, bty) + hitp(rv[i].w, btx, bty);
    #pragma unroll
    for (int d = 1; d < 64; d <<= 1) cnt += __shfl_xor(cnt, d);
    if (lane == 0) woff[w] = cnt;
    __syncthreads();

    int offs = (w == 1) ? woff[0] : 0;
    const int N = min(woff[0] + woff[1], CAP);

    // ---- Phase 1, pass B: ballot compaction ----
    const unsigned long long lt = (1ull << lane) - 1ull;
    #pragma unroll
    for (int i = 0; i < 16; ++i) {
        int gbase = wbase + i * 256 + lane * 4;
        int h0 = hitp(rv[i].x, btx, bty), h1 = hitp(rv[i].y, btx, bty);
        int h2 = hitp(rv[i].z, btx, bty), h3 = hitp(rv[i].w, btx, bty);
        unsigned long long m0 = __ballot(h0), m1 = __ballot(h1);
        unsigned long long m2 = __ballot(h2), m3 = __ballot(h3);
        int pos = offs + __popcll(m0 & lt) + __popcll(m1 & lt)
                       + __popcll(m2 & lt) + __popcll(m3 & lt);
        if (h0) { if (pos < CAP) slist[pos] = (unsigned short)(gbase    ); pos++; }
        if (h1) { if (pos < CAP) slist[pos] = (unsigned short)(gbase + 1); pos++; }
        if (h2) { if (pos < CAP) slist[pos] = (unsigned short)(gbase + 2); pos++; }
        if (h3) { if (pos < CAP) slist[pos] = (unsigned short)(gbase + 3); pos++; }
        offs += __popcll(m0) + __popcll(m1) + __popcll(m2) + __popcll(m3);
    }
    __syncthreads();

    // ---- Phase 2: rank sort, 32-bit keys + position tiebreak ----
    unsigned short myidx[8]; unsigned int mykey[8]; int myr[8];
    #pragma unroll
    for (int m = 0; m < 8; ++m) {
        int i = t + m * BLKT;
        if (i < N) {
            unsigned idx = slist[i];
            unsigned k = __float_as_uint(depths[idx]);   // depths > 0
            myidx[m] = (unsigned short)idx; mykey[m] = k; fkeys[i] = k;
        }
    }
    if (t < 4) fkeys[N + t] = 0xFFFFFFFFu;   // pad: never counts as "<"
    __syncthreads();

    const uint4* fk4 = (const uint4*)fkeys;
    const int nj4 = (N + 3) >> 2;
    #pragma unroll
    for (int m = 0; m < 8; ++m) {
        int i = t + m * BLKT;
        if (i < N) {
            unsigned ke = mykey[m]; int r = 0;
            for (int j4 = 0; j4 < nj4; ++j4) {
                uint4 kv = fk4[j4]; int j = j4 << 2;
                r += (int)((kv.x < ke) | ((kv.x == ke) & (j     < i)));
                r += (int)((kv.y < ke) | ((kv.y == ke) & (j + 1 < i)));
                r += (int)((kv.z < ke) | ((kv.z == ke) & (j + 2 < i)));
                r += (int)((kv.w < ke) | ((kv.w == ke) & (j + 3 < i)));
            }
            myr[m] = r;
        }
    }
    __syncthreads();
    #pragma unroll
    for (int m = 0; m < 8; ++m) {
        int i = t + m * BLKT;
        if (i < N) slist[myr[m]] = myidx[m];
    }
    if (t < 4) slist[N + t] = (unsigned short)G;   // pad -> zero record
    __syncthreads();

    // ---- Phase 3: composite (scalar-pipe records, 2 px/lane) ----
    // wave w owns rows [w*8, w*8+8) of the tile; lane -> x = lane&15,
    // row pair = (lane>>4)*2 + {0,1}.
    const float px  = (float)(btx * TILE + (lane & 15)) + 0.5f;
    const int   ry  = lane >> 4;
    const float py0 = (float)(bty * TILE + w * 8 + ry * 2) + 0.5f;
    const float py1 = py0 + 1.0f;

    float T0 = 1.0f, T1 = 1.0f;
    float ar0 = 0.f, ag0 = 0.f, ab0 = 0.f;
    float ar1 = 0.f, ag1 = 0.f, ab1 = 0.f;

    for (int base = 0; base < N; base += 4) {
        ushort4 s4 = *(const ushort4*)&slist[base];   // 1 ds_read_b64 / 4
        unsigned short sv[4] = { s4.x, s4.y, s4.z, s4.w };
        #pragma unroll
        for (int u = 0; u < 4; ++u) {
            // wave-uniform index -> record loads go to the SMEM pipe
            int idx = __builtin_amdgcn_readfirstlane((int)sv[u]);
            const float* r = tbl + (idx << 4);
            float dx = px - r[0];
            float dy0 = py0 - r[1], dy1 = py1 - r[1];
            // per-pixel expression tree identical to validated version
            float sg0 = fmaf(r[2], dx*dx, fmaf(r[4], dy0*dy0, r[3] * (dx*dy0)));
            float sg1 = fmaf(r[2], dx*dx, fmaf(r[4], dy1*dy1, r[3] * (dx*dy1)));
            float al0 = r[5] * __expf(-sg0);
            float al1 = r[5] * __expf(-sg1);
            bool ok0 = (sg0 >= 0.0f) && (al0 >= ALPHA_THRESH);
            bool ok1 = (sg1 >= 0.0f) && (al1 >= ALPHA_THRESH);
            al0 = ok0 ? fminf(al0, ALPHA_CAP) : 0.0f;
            al1 = ok1 ? fminf(al1, ALPHA_CAP) : 0.0f;
            float w0 = al0 * T0, w1 = al1 * T1;
            ar0 = fmaf(w0, r[6], ar0);  ar1 = fmaf(w1, r[6], ar1);
            ag0 = fmaf(w0, r[7], ag0);  ag1 = fmaf(w1, r[7], ag1);
            ab0 = fmaf(w0, r[8], ab0);  ab1 = fmaf(w1, r[8], ab1);
            T0 *= (1.0f - al0);         // matches reference rounding
            T1 *= (1.0f - al1);
        }
        // per-wave deferred exit: residual contributions telescope to
        // <= T < 1e-4 per channel -> within tolerance. No barriers.
        if (__all((T0 < TRANS_THRESH) & (T1 < TRANS_THRESH))) break;
    }

    const int ox = (int)btx * TILE + (lane & 15);
    const int oy = (int)bty * TILE + w * 8 + ry * 2;
    const int o = (oy * IMG_W + ox) * 3;
    out[o]     = ar0;
    out[o + 1] = ag0;
    out[o + 2] = ab0;                 // BG = 0 -> t_rem term vanishes
    out[o + 3*IMG_W]     = ar1;       // row oy+1
    out[o + 3*IMG_W + 1] = ag1;
    out[o + 3*IMG_W + 2] = ab1;
}

extern "C" void kernel_launch(void* const* d_in, const int* in_sizes, int n_in,
                              void* d_out, int out_size, void* d_ws, size_t ws_size,
                              hipStream_t stream)
{
    const float* means2d = (const float*)d_in[0];  // (G,2)
    const float* conics  = (const float*)d_in[1];  // (G,3)
    const float* colors  = (const float*)d_in[2];  // (G,3)
    const float* opac    = (const float*)d_in[3];  // (G,)
    const float* depths  = (const float*)d_in[4];  // (G,)
    float* out = (float*)d_out;
    unsigned int* ranges = (unsigned int*)d_ws;                 // 32 KB
    float* tbl = (float*)((char*)d_ws + 32 * 1024);             // (G+1)*64 B

    range_kernel<<<G / BLK, BLK, 0, stream>>>(means2d, conics, colors, opac,
                                              ranges, tbl);
    tile_kernel<<<dim3(NTX, NTY), dim3(BLKT), 0, stream>>>(
        ranges, depths, tbl, out);
}

// Round 5
// 97.515 us; speedup vs baseline: 1.0099x; 1.0099x over previous
//
#include <hip/hip_runtime.h>

#define G 8192
#define IMG_W 512
#define IMG_H 512
#define TILE 16
#define NTX (IMG_W / TILE)
#define NTY (IMG_H / TILE)
#define BLK 256             // range kernel block
#define BLKT 128            // tile kernel block: 2 waves, 2 px per lane
#define CAP 1024            // per-tile list capacity (avg ~190)
#define ALPHA_THRESH (1.0f/255.0f)
#define ALPHA_CAP 0.99f
#define TRANS_THRESH 1e-4f

// -----------------------------------------------------------------------
// Kernel 0: per-gaussian tile-span (exact conservative cull, packed u32)
// PLUS a packed 64B record per gaussian:
//   f4[0]=(mx,my,0.5a,b)  f4[1]=(0.5c,op,cr,cg)  f4[2]=(cb,0,0,0)
// Record G (index 8192) is all-zero: op=0 -> exact no-op pad gaussian.
// -----------------------------------------------------------------------
__global__ __launch_bounds__(BLK)
void range_kernel(const float* __restrict__ means2d,
                  const float* __restrict__ conics,
                  const float* __restrict__ colors,
                  const float* __restrict__ opac,
                  unsigned int* __restrict__ ranges,
                  float* __restrict__ tbl)
{
    int g = blockIdx.x * BLK + threadIdx.x;
    if (g >= G) return;
    float op = opac[g];
    float a  = conics[3*g], b = conics[3*g+1], c = conics[3*g+2];
    float mx = means2d[2*g], my = means2d[2*g+1];
    float cr = colors[3*g], cg = colors[3*g+1], cb = colors[3*g+2];

    float4* t4 = (float4*)(tbl + (g << 4));
    t4[0] = make_float4(mx, my, 0.5f * a, b);
    t4[1] = make_float4(0.5f * c, op, cr, cg);
    t4[2] = make_float4(cb, 0.0f, 0.0f, 0.0f);
    if (g == 0) {                       // zero pad-record at index G
        float4* z = (float4*)(tbl + (G << 4));
        z[0] = z[1] = z[2] = make_float4(0.0f, 0.0f, 0.0f, 0.0f);
    }

    unsigned int packed = 0xFFu;          // default: culled
    if (op * 255.0f >= 1.0f) {
        float smax = __logf(op * 255.0f);
        float det = fmaxf(a * c - b * b, 1e-12f);
        float rx = sqrtf(fmaxf(2.0f * smax * c / det, 0.0f)) * 1.0001f + 0.01f;
        float ry = sqrtf(fmaxf(2.0f * smax * a / det, 0.0f)) * 1.0001f + 0.01f;
        int txmin = (int)ceilf ((mx - rx - 15.5f) * 0.0625f);
        int txmax = (int)floorf((mx + rx -  0.5f) * 0.0625f);
        int tymin = (int)ceilf ((my - ry - 15.5f) * 0.0625f);
        int tymax = (int)floorf((my + ry -  0.5f) * 0.0625f);
        if (!(txmax < 0 || txmin > NTX-1 || tymax < 0 || tymin > NTY-1 ||
              txmin > txmax || tymin > tymax)) {
            txmin = max(txmin, 0); txmax = min(txmax, NTX-1);
            tymin = max(tymin, 0); tymax = min(tymax, NTY-1);
            packed = (unsigned)txmin | ((unsigned)txmax << 8)
                   | ((unsigned)tymin << 16) | ((unsigned)tymax << 24);
        }
    }
    ranges[g] = packed;
}

__device__ __forceinline__ int hitp(unsigned p, unsigned btx, unsigned bty)
{
    return (btx >= (p & 0xffu)) & (btx <= ((p >> 8) & 0xffu)) &
           (bty >= ((p >> 16) & 0xffu)) & (bty <= (p >> 24));
}

// ---- phase-3 register double-buffering (all names static: rule #20) ----
#define DECL_GRP(P) \
    float4 P##0a, P##0b, P##1a, P##1b, P##2a, P##2b, P##3a, P##3b; \
    float  P##0c, P##1c, P##2c, P##3c;

// 4 records via uniform vector addresses (one broadcast L2 req per load)
#define LOAD_GRP(P, s4) { \
    const float4* b0 = (const float4*)(tbl + ((int)(s4).x << 4)); \
    const float4* b1 = (const float4*)(tbl + ((int)(s4).y << 4)); \
    const float4* b2 = (const float4*)(tbl + ((int)(s4).z << 4)); \
    const float4* b3 = (const float4*)(tbl + ((int)(s4).w << 4)); \
    P##0a = b0[0]; P##0b = b0[1]; P##0c = ((const float*)b0)[8]; \
    P##1a = b1[0]; P##1b = b1[1]; P##1c = ((const float*)b1)[8]; \
    P##2a = b2[0]; P##2b = b2[1]; P##2c = ((const float*)b2)[8]; \
    P##3a = b3[0]; P##3b = b3[1]; P##3c = ((const float*)b3)[8]; }

// per-pixel expression tree identical to the validated version
#define COMP1(pa, pb, pcb) { \
    float dx  = px - pa.x; \
    float dy0 = py0 - pa.y, dy1 = py1 - pa.y; \
    float dxdx = dx * dx; \
    float sg0 = fmaf(pa.z, dxdx, fmaf(pb.x, dy0*dy0, pa.w * (dx*dy0))); \
    float sg1 = fmaf(pa.z, dxdx, fmaf(pb.x, dy1*dy1, pa.w * (dx*dy1))); \
    float al0 = pb.y * __expf(-sg0); \
    float al1 = pb.y * __expf(-sg1); \
    bool ok0 = (sg0 >= 0.0f) && (al0 >= ALPHA_THRESH); \
    bool ok1 = (sg1 >= 0.0f) && (al1 >= ALPHA_THRESH); \
    al0 = ok0 ? fminf(al0, ALPHA_CAP) : 0.0f; \
    al1 = ok1 ? fminf(al1, ALPHA_CAP) : 0.0f; \
    float w0 = al0 * T0, w1 = al1 * T1; \
    ar0 = fmaf(w0, pb.z, ar0);  ar1 = fmaf(w1, pb.z, ar1); \
    ag0 = fmaf(w0, pb.w, ag0);  ag1 = fmaf(w1, pb.w, ag1); \
    ab0 = fmaf(w0, pcb,  ab0);  ab1 = fmaf(w1, pcb,  ab1); \
    T0 *= (1.0f - al0); \
    T1 *= (1.0f - al1); }

// -----------------------------------------------------------------------
// Kernel 1 (one 128-thread block per 16x16 tile; 2 waves; 2 px per lane):
//  Phase 1: two-pass scan (16 uint4/lane in registers) + ballot
//           compaction in gaussian-index order.
//  Phase 2: rank sort, 32-bit float-bit keys, POSITION tiebreak; keys
//           read as uint4 -> 1 ds_read_b128 per 4 comparisons.
//  Phase 3: depth-2 software pipeline. While computing group k from
//           register set A, the 12 VMEM loads for group k+1 fill set B
//           and the slist indices for k+2 are in flight on DS. Breaks
//           the serial ds_read->s_load->wait->compute chain that left
//           ~25 us of exposed latency at 2 waves/SIMD. Tail padded with
//           16 zero-records -> branchless pipelined reads.
// -----------------------------------------------------------------------
__global__ __launch_bounds__(BLKT)
void tile_kernel(const unsigned int* __restrict__ ranges,
                 const float* __restrict__ depths,
                 const float* __restrict__ tbl,
                 float*       __restrict__ out)
{
    __shared__ __align__(16) unsigned short slist[CAP + 16];
    __shared__ __align__(16) unsigned int fkeys[CAP + 8];
    __shared__ int woff[2];

    const int t = threadIdx.x;
    const int lane = t & 63, w = t >> 6;          // w in {0,1}
    const unsigned btx = blockIdx.x, bty = blockIdx.y;

    // ---- Phase 1, pass A: load + count (no barriers) ----
    const uint4* r4 = (const uint4*)ranges;
    const int wbase = w * (G / 2);                // 4096 gaussians per wave
    uint4 rv[16];
    #pragma unroll
    for (int i = 0; i < 16; ++i)
        rv[i] = r4[(wbase >> 2) + i * 64 + lane];

    int cnt = 0;
    #pragma unroll
    for (int i = 0; i < 16; ++i)
        cnt += hitp(rv[i].x, btx, bty) + hitp(rv[i].y, btx, bty)
             + hitp(rv[i].z, btx, bty) + hitp(rv[i].w, btx, bty);
    #pragma unroll
    for (int d = 1; d < 64; d <<= 1) cnt += __shfl_xor(cnt, d);
    if (lane == 0) woff[w] = cnt;
    __syncthreads();

    int offs = (w == 1) ? woff[0] : 0;
    const int N = min(woff[0] + woff[1], CAP);

    // ---- Phase 1, pass B: ballot compaction ----
    const unsigned long long lt = (1ull << lane) - 1ull;
    #pragma unroll
    for (int i = 0; i < 16; ++i) {
        int gbase = wbase + i * 256 + lane * 4;
        int h0 = hitp(rv[i].x, btx, bty), h1 = hitp(rv[i].y, btx, bty);
        int h2 = hitp(rv[i].z, btx, bty), h3 = hitp(rv[i].w, btx, bty);
        unsigned long long m0 = __ballot(h0), m1 = __ballot(h1);
        unsigned long long m2 = __ballot(h2), m3 = __ballot(h3);
        int pos = offs + __popcll(m0 & lt) + __popcll(m1 & lt)
                       + __popcll(m2 & lt) + __popcll(m3 & lt);
        if (h0) { if (pos < CAP) slist[pos] = (unsigned short)(gbase    ); pos++; }
        if (h1) { if (pos < CAP) slist[pos] = (unsigned short)(gbase + 1); pos++; }
        if (h2) { if (pos < CAP) slist[pos] = (unsigned short)(gbase + 2); pos++; }
        if (h3) { if (pos < CAP) slist[pos] = (unsigned short)(gbase + 3); pos++; }
        offs += __popcll(m0) + __popcll(m1) + __popcll(m2) + __popcll(m3);
    }
    __syncthreads();

    // ---- Phase 2: rank sort, 32-bit keys + position tiebreak ----
    unsigned short myidx[8]; unsigned int mykey[8]; int myr[8];
    #pragma unroll
    for (int m = 0; m < 8; ++m) {
        int i = t + m * BLKT;
        if (i < N) {
            unsigned idx = slist[i];
            unsigned k = __float_as_uint(depths[idx]);   // depths > 0
            myidx[m] = (unsigned short)idx; mykey[m] = k; fkeys[i] = k;
        }
    }
    if (t < 8) fkeys[N + t] = 0xFFFFFFFFu;   // pad: never counts as "<"
    __syncthreads();

    const uint4* fk4 = (const uint4*)fkeys;
    const int nj4 = (N + 3) >> 2;
    #pragma unroll
    for (int m = 0; m < 8; ++m) {
        int i = t + m * BLKT;
        if (i < N) {
            unsigned ke = mykey[m]; int r = 0;
            for (int j4 = 0; j4 < nj4; ++j4) {
                uint4 kv = fk4[j4]; int j = j4 << 2;
                r += (int)((kv.x < ke) | ((kv.x == ke) & (j     < i)));
                r += (int)((kv.y < ke) | ((kv.y == ke) & (j + 1 < i)));
                r += (int)((kv.z < ke) | ((kv.z == ke) & (j + 2 < i)));
                r += (int)((kv.w < ke) | ((kv.w == ke) & (j + 3 < i)));
            }
            myr[m] = r;
        }
    }
    __syncthreads();
    #pragma unroll
    for (int m = 0; m < 8; ++m) {
        int i = t + m * BLKT;
        if (i < N) slist[myr[m]] = myidx[m];
    }
    if (t < 16) slist[N + t] = (unsigned short)G;   // pads -> zero record
    __syncthreads();

    // ---- Phase 3: composite, depth-2 pipelined (2 px/lane) ----
    // wave w owns rows [w*8, w*8+8); lane -> x = lane&15, rows 2*(lane>>4)+{0,1}
    const float px  = (float)(btx * TILE + (lane & 15)) + 0.5f;
    const int   ry  = lane >> 4;
    const float py0 = (float)(bty * TILE + w * 8 + ry * 2) + 0.5f;
    const float py1 = py0 + 1.0f;

    float T0 = 1.0f, T1 = 1.0f;
    float ar0 = 0.f, ag0 = 0.f, ab0 = 0.f;
    float ar1 = 0.f, ag1 = 0.f, ab1 = 0.f;

    DECL_GRP(A) DECL_GRP(B)
    ushort4 sB;
    {
        ushort4 sA = *(const ushort4*)&slist[0];
        sB = *(const ushort4*)&slist[4];
        LOAD_GRP(A, sA)                    // prologue fill, stage A
    }

    const int nb = (N + 7) & ~7;
    for (int base = 0; base < nb; base += 8) {
        // indices two groups ahead (DS latency hidden under compute)
        ushort4 sA2 = *(const ushort4*)&slist[base + 8];
        ushort4 sB2 = *(const ushort4*)&slist[base + 12];
        LOAD_GRP(B, sB)                    // VMEM for group base+4 in flight
        COMP1(A0a, A0b, A0c)               // compute group base from regs
        COMP1(A1a, A1b, A1c)
        COMP1(A2a, A2b, A2c)
        COMP1(A3a, A3b, A3c)
        LOAD_GRP(A, sA2)                   // VMEM for group base+8 in flight
        COMP1(B0a, B0b, B0c)               // compute group base+4
        COMP1(B1a, B1b, B1c)
        COMP1(B2a, B2b, B2c)
        COMP1(B3a, B3b, B3c)
        sB = sB2;
        // per-wave deferred exit: residual contributions telescope to
        // <= T < 1e-4 per channel -> within tolerance. No barriers.
        if (__all((T0 < TRANS_THRESH) & (T1 < TRANS_THRESH))) break;
    }

    const int ox = (int)btx * TILE + (lane & 15);
    const int oy = (int)bty * TILE + w * 8 + ry * 2;
    const int o = (oy * IMG_W + ox) * 3;
    out[o]     = ar0;
    out[o + 1] = ag0;
    out[o + 2] = ab0;                 // BG = 0 -> t_rem term vanishes
    out[o + 3*IMG_W]     = ar1;       // row oy+1
    out[o + 3*IMG_W + 1] = ag1;
    out[o + 3*IMG_W + 2] = ab1;
}

extern "C" void kernel_launch(void* const* d_in, const int* in_sizes, int n_in,
                              void* d_out, int out_size, void* d_ws, size_t ws_size,
                              hipStream_t stream)
{
    const float* means2d = (const float*)d_in[0];  // (G,2)
    const float* conics  = (const float*)d_in[1];  // (G,3)
    const float* colors  = (const float*)d_in[2];  // (G,3)
    const float* opac    = (const float*)d_in[3];  // (G,)
    const float* depths  = (const float*)d_in[4];  // (G,)
    float* out = (float*)d_out;
    unsigned int* ranges = (unsigned int*)d_ws;                 // 32 KB
    float* tbl = (float*)((char*)d_ws + 32 * 1024);             // (G+1)*64 B

    range_kernel<<<G / BLK, BLK, 0, stream>>>(means2d, conics, colors, opac,
                                              ranges, tbl);
    tile_kernel<<<dim3(NTX, NTY), dim3(BLKT), 0, stream>>>(
        ranges, depths, tbl, out);
}

// Round 6
// 94.100 us; speedup vs baseline: 1.0465x; 1.0363x over previous
//
#include <hip/hip_runtime.h>

#define G 8192
#define IMG_W 512
#define IMG_H 512
#define TW 16               // tile width  (px)
#define TH 32               // tile height (px)
#define NTX (IMG_W / TW)    // 32
#define NTY (IMG_H / TH)    // 16
#define BLK 256
#define CAP 2048            // per-tile list capacity (16x32 avg ~270)
#define ALPHA_THRESH (1.0f/255.0f)
#define ALPHA_CAP 0.99f
#define TRANS_THRESH 1e-4f

// -----------------------------------------------------------------------
// Kernel 0: per-gaussian tile-span for the 16x32 tile grid (exact
// conservative cull, packed u32: txmin,txmax,tymin,tymax bytes) PLUS a
// packed 64B record per gaussian:
//   f4[0]=(mx,my,0.5a,b)  f4[1]=(0.5c,op,cr,cg)  f4[2]=(cb,0,0,0)
// -----------------------------------------------------------------------
__global__ __launch_bounds__(BLK)
void range_kernel(const float* __restrict__ means2d,
                  const float* __restrict__ conics,
                  const float* __restrict__ colors,
                  const float* __restrict__ opac,
                  unsigned int* __restrict__ ranges,
                  float* __restrict__ tbl)
{
    int g = blockIdx.x * BLK + threadIdx.x;
    if (g >= G) return;
    float op = opac[g];
    float a  = conics[3*g], b = conics[3*g+1], c = conics[3*g+2];
    float mx = means2d[2*g], my = means2d[2*g+1];
    float cr = colors[3*g], cg = colors[3*g+1], cb = colors[3*g+2];

    float4* t4 = (float4*)(tbl + (g << 4));
    t4[0] = make_float4(mx, my, 0.5f * a, b);
    t4[1] = make_float4(0.5f * c, op, cr, cg);
    t4[2] = make_float4(cb, 0.0f, 0.0f, 0.0f);

    unsigned int packed = 0xFFu;          // default: culled (txmin>txmax)
    if (op * 255.0f >= 1.0f) {
        float smax = __logf(op * 255.0f);
        float det = fmaxf(a * c - b * b, 1e-12f);
        float rx = sqrtf(fmaxf(2.0f * smax * c / det, 0.0f)) * 1.0001f + 0.01f;
        float ry = sqrtf(fmaxf(2.0f * smax * a / det, 0.0f)) * 1.0001f + 0.01f;
        int txmin = (int)ceilf ((mx - rx - 15.5f) * 0.0625f);    // /16
        int txmax = (int)floorf((mx + rx -  0.5f) * 0.0625f);
        int tymin = (int)ceilf ((my - ry - 31.5f) * 0.03125f);   // /32
        int tymax = (int)floorf((my + ry -  0.5f) * 0.03125f);
        if (!(txmax < 0 || txmin > NTX-1 || tymax < 0 || tymin > NTY-1 ||
              txmin > txmax || tymin > tymax)) {
            txmin = max(txmin, 0); txmax = min(txmax, NTX-1);
            tymin = max(tymin, 0); tymax = min(tymax, NTY-1);
            packed = (unsigned)txmin | ((unsigned)txmax << 8)
                   | ((unsigned)tymin << 16) | ((unsigned)tymax << 24);
        }
    }
    ranges[g] = packed;
}

__device__ __forceinline__ int hitp(unsigned p, unsigned btx, unsigned bty)
{
    return (btx >= (p & 0xffu)) & (btx <= ((p >> 8) & 0xffu)) &
           (bty >= ((p >> 16) & 0xffu)) & (bty <= (p >> 24));
}

// -----------------------------------------------------------------------
// Kernel 1 (one 256-thread block per 16x32 tile; 4 waves; 2 px/lane):
//  R0's validated structure with a taller tile: per-CU DS-broadcast work
//  drops to ~0.70x (8 waves/CU x ~266-list vs 16 x ~190) and each 36B
//  LDS broadcast now feeds 2 pixels.
//  Phase 1: barrier-free two-pass scan + ballot compaction (idx order).
//  Phase 2: rank sort, 32-bit float-bit keys, POSITION tiebreak; keys
//           read as uint4.
//  Phase 3: chunked LDS staging (3 loads/record from packed tbl), packed
//           float4 broadcasts, strip-mined x4 with deferred exit, block
//           exit via __syncthreads_and.
// -----------------------------------------------------------------------
__global__ __launch_bounds__(BLK)
void tile_kernel(const unsigned int* __restrict__ ranges,
                 const float* __restrict__ depths,
                 const float* __restrict__ tbl,
                 float*       __restrict__ out)
{
    __shared__ __align__(16) unsigned short slist[CAP];
    __shared__ __align__(16) unsigned int fkeys[CAP + 8];
    __shared__ int woff[4];
    __shared__ float4 sq0[BLK];   // mx, my, 0.5a, b
    __shared__ float4 sq1[BLK];   // 0.5c, op, r, g
    __shared__ float  sq2[BLK];   // blue

    const int t = threadIdx.x;
    const int lane = t & 63, w = t >> 6;
    const unsigned btx = blockIdx.x, bty = blockIdx.y;

    // ---- Phase 1, pass A: load + count (no barriers) ----
    const uint4* r4 = (const uint4*)ranges;
    const int wbase = w * (G / 4);            // 2048 gaussians per wave
    uint4 rv[8];
    #pragma unroll
    for (int i = 0; i < 8; ++i)
        rv[i] = r4[(wbase >> 2) + i * 64 + lane];

    int cnt = 0;
    #pragma unroll
    for (int i = 0; i < 8; ++i)
        cnt += hitp(rv[i].x, btx, bty) + hitp(rv[i].y, btx, bty)
             + hitp(rv[i].z, btx, bty) + hitp(rv[i].w, btx, bty);
    #pragma unroll
    for (int d = 1; d < 64; d <<= 1) cnt += __shfl_xor(cnt, d);
    if (lane == 0) woff[w] = cnt;
    __syncthreads();

    int offs = 0;
    for (int ww = 0; ww < w; ++ww) offs += woff[ww];
    const int N = min(woff[0] + woff[1] + woff[2] + woff[3], CAP);

    // ---- Phase 1, pass B: ballot compaction ----
    const unsigned long long lt = (1ull << lane) - 1ull;
    #pragma unroll
    for (int i = 0; i < 8; ++i) {
        int gbase = wbase + i * 256 + lane * 4;
        int h0 = hitp(rv[i].x, btx, bty), h1 = hitp(rv[i].y, btx, bty);
        int h2 = hitp(rv[i].z, btx, bty), h3 = hitp(rv[i].w, btx, bty);
        unsigned long long m0 = __ballot(h0), m1 = __ballot(h1);
        unsigned long long m2 = __ballot(h2), m3 = __ballot(h3);
        int pos = offs + __popcll(m0 & lt) + __popcll(m1 & lt)
                       + __popcll(m2 & lt) + __popcll(m3 & lt);
        if (h0) { if (pos < CAP) slist[pos] = (unsigned short)(gbase    ); pos++; }
        if (h1) { if (pos < CAP) slist[pos] = (unsigned short)(gbase + 1); pos++; }
        if (h2) { if (pos < CAP) slist[pos] = (unsigned short)(gbase + 2); pos++; }
        if (h3) { if (pos < CAP) slist[pos] = (unsigned short)(gbase + 3); pos++; }
        offs += __popcll(m0) + __popcll(m1) + __popcll(m2) + __popcll(m3);
    }
    __syncthreads();

    // ---- Phase 2: rank sort, 32-bit keys + position tiebreak ----
    unsigned short myidx[8]; unsigned int mykey[8]; int myr[8];
    #pragma unroll
    for (int m = 0; m < 8; ++m) {
        int i = t + m * BLK;
        if (i < N) {
            unsigned idx = slist[i];
            unsigned k = __float_as_uint(depths[idx]);   // depths > 0
            myidx[m] = (unsigned short)idx; mykey[m] = k; fkeys[i] = k;
        }
    }
    if (t < 8) fkeys[N + t] = 0xFFFFFFFFu;   // pad: never counts as "<"
    __syncthreads();

    const uint4* fk4 = (const uint4*)fkeys;
    const int nj4 = (N + 3) >> 2;
    #pragma unroll
    for (int m = 0; m < 8; ++m) {
        int i = t + m * BLK;
        if (i < N) {
            unsigned ke = mykey[m]; int r = 0;
            for (int j4 = 0; j4 < nj4; ++j4) {
                uint4 kv = fk4[j4]; int j = j4 << 2;
                r += (int)((kv.x < ke) | ((kv.x == ke) & (j     < i)));
                r += (int)((kv.y < ke) | ((kv.y == ke) & (j + 1 < i)));
                r += (int)((kv.z < ke) | ((kv.z == ke) & (j + 2 < i)));
                r += (int)((kv.w < ke) | ((kv.w == ke) & (j + 3 < i)));
            }
            myr[m] = r;
        }
    }
    __syncthreads();
    #pragma unroll
    for (int m = 0; m < 8; ++m) {
        int i = t + m * BLK;
        if (i < N) slist[myr[m]] = myidx[m];
    }
    __syncthreads();

    // ---- Phase 3: composite (LDS-staged broadcasts, 2 px/lane) ----
    // lane -> x = t&15, rows 2*(t>>4) + {0,1}  (covers 16x32)
    const float px  = (float)(btx * TW + (t & 15)) + 0.5f;
    const float py0 = (float)(bty * TH + (t >> 4) * 2) + 0.5f;
    const float py1 = py0 + 1.0f;

    float T0 = 1.0f, T1 = 1.0f;
    float ar0 = 0.f, ag0 = 0.f, ab0 = 0.f;
    float ar1 = 0.f, ag1 = 0.f, ab1 = 0.f;
    bool done = false;

    for (int base = 0; base < N; base += BLK) {
        int n = min(BLK, N - base);
        // stage from packed tbl (3 loads/record); slots >= n are exact
        // zero-gaussians (op=0 -> alpha 0 no-ops)
        float4 v0 = make_float4(0.f, 0.f, 0.f, 0.f);
        float4 v1 = make_float4(0.f, 0.f, 0.f, 0.f);
        float  v2 = 0.f;
        if (t < n) {
            int idx = slist[base + t];
            const float4* b = (const float4*)(tbl + (idx << 4));
            v0 = b[0]; v1 = b[1]; v2 = ((const float*)b)[8];
        }
        sq0[t] = v0; sq1[t] = v1; sq2[t] = v2;
        __syncthreads();

        if (!done) {
            int n4 = (n + 3) & ~3;        // padded slots are no-ops
            for (int i = 0; i < n4 && !done; i += 4) {
                #pragma unroll
                for (int u = 0; u < 4; ++u) {
                    float4 q0 = sq0[i + u];     // ds_read_b128 (broadcast)
                    float4 q1 = sq1[i + u];     // ds_read_b128 (broadcast)
                    float  bl = sq2[i + u];     // ds_read_b32
                    float dx  = px  - q0.x;
                    float dy0 = py0 - q0.y, dy1 = py1 - q0.y;
                    float dxdx = dx * dx;
                    // per-pixel expression tree identical to validated ver.
                    float sg0 = fmaf(q0.z, dxdx,
                                fmaf(q1.x, dy0*dy0, q0.w * (dx*dy0)));
                    float sg1 = fmaf(q0.z, dxdx,
                                fmaf(q1.x, dy1*dy1, q0.w * (dx*dy1)));
                    float al0 = q1.y * __expf(-sg0);
                    float al1 = q1.y * __expf(-sg1);
                    bool ok0 = (sg0 >= 0.0f) && (al0 >= ALPHA_THRESH);
                    bool ok1 = (sg1 >= 0.0f) && (al1 >= ALPHA_THRESH);
                    al0 = ok0 ? fminf(al0, ALPHA_CAP) : 0.0f;
                    al1 = ok1 ? fminf(al1, ALPHA_CAP) : 0.0f;
                    float w0 = al0 * T0, w1 = al1 * T1;
                    ar0 = fmaf(w0, q1.z, ar0);  ar1 = fmaf(w1, q1.z, ar1);
                    ag0 = fmaf(w0, q1.w, ag0);  ag1 = fmaf(w1, q1.w, ag1);
                    ab0 = fmaf(w0, bl,   ab0);  ab1 = fmaf(w1, bl,   ab1);
                    T0 *= (1.0f - al0);         // matches reference rounding
                    T1 *= (1.0f - al1);
                }
                // deferred exit: <=3 extra gaussians, each weighted < 1e-4
                if ((T0 < TRANS_THRESH) & (T1 < TRANS_THRESH)) done = true;
            }
        }
        if (__syncthreads_and((int)done)) break;
    }

    const int ox = (int)btx * TW + (t & 15);
    const int oy = (int)bty * TH + (t >> 4) * 2;
    const int o = (oy * IMG_W + ox) * 3;
    out[o]     = ar0;
    out[o + 1] = ag0;
    out[o + 2] = ab0;                 // BG = 0 -> t_rem term vanishes
    out[o + 3*IMG_W]     = ar1;       // row oy+1
    out[o + 3*IMG_W + 1] = ag1;
    out[o + 3*IMG_W + 2] = ab1;
}

extern "C" void kernel_launch(void* const* d_in, const int* in_sizes, int n_in,
                              void* d_out, int out_size, void* d_ws, size_t ws_size,
                              hipStream_t stream)
{
    const float* means2d = (const float*)d_in[0];  // (G,2)
    const float* conics  = (const float*)d_in[1];  // (G,3)
    const float* colors  = (const float*)d_in[2];  // (G,3)
    const float* opac    = (const float*)d_in[3];  // (G,)
    const float* depths  = (const float*)d_in[4];  // (G,)
    float* out = (float*)d_out;
    unsigned int* ranges = (unsigned int*)d_ws;                 // 32 KB
    float* tbl = (float*)((char*)d_ws + 32 * 1024);             // G*64 B

    range_kernel<<<G / BLK, BLK, 0, stream>>>(means2d, conics, colors, opac,
                                              ranges, tbl);
    tile_kernel<<<dim3(NTX, NTY), dim3(BLK), 0, stream>>>(
        ranges, depths, tbl, out);
}